// Round 3
// baseline (195.321 us; speedup 1.0000x reference)
//
#include <hip/hip_runtime.h>

// Depthwise 11x11 box blur, reflect padding, fp32, (16,64,256,256).
// Separable: out = kv * Hsum11(Vsum11(x)). One block per (image, 32-row tile).
//
// Stage A: thread = column. 42 coalesced 4B global loads (row-reflect),
//          vertical sliding 11-sum in a register ring. Writes colsum rows to
//          LDS padded to 272 floats/row (8 reflected cols each side), so
//          stage B needs no reflect logic and reads stay 16B-aligned.
// Stage B: lane owns 4 consecutive output columns of one row (row is
//          wave-uniform). 5 x ds_read_b128 fetch the 20-float window,
//          sliding-sum -> 4 outputs -> one float4 global store (1KB/wave).
//          LDS-pipe cost drops ~4.25x vs 11 x ds_read_b32 per output.

#define KS      11
#define PAD     5
#define IMG_H   256
#define IMG_W   256
#define TILE_H  32
#define NTILES  (IMG_H / TILE_H)      // 8
#define RAW_ROWS (TILE_H + 2 * PAD)   // 42
#define CSP     272                   // 8 pad + 256 + 8 pad

__global__ __launch_bounds__(256, 4)
void blur_box11_kernel(const float* __restrict__ in,
                       const float* __restrict__ kern,
                       float* __restrict__ out) {
    __shared__ float cs[TILE_H * CSP];             // 34,816 B

    const int tid = threadIdx.x;
    const int img = blockIdx.x >> 3;               // / NTILES
    const int ty0 = (blockIdx.x & (NTILES - 1)) * TILE_H;

    const float* src = in + (size_t)img * (IMG_H * IMG_W);
    float*       dst = out + (size_t)img * (IMG_H * IMG_W);
    const float  kv  = kern[0];                    // 1/121 (uniform box)

    // ---- Stage A: fused load + vertical sliding 11-sum, padded LDS write ----
    {
        const int x = tid;                         // thread = column
        float cb[KS];                              // register ring, static idx
        float s = 0.0f;
#pragma unroll
        for (int r = 0; r < RAW_ROWS; ++r) {
            int sr = ty0 + r - PAD;                // wave-uniform row index
            sr = (sr < 0) ? -sr : ((sr > IMG_H - 1) ? 2 * (IMG_H - 1) - sr : sr);
            float v = src[sr * IMG_W + x];         // coalesced 4B/lane
            s += v;
            if (r >= KS) s -= cb[r % KS];
            cb[r % KS] = v;
            if (r >= KS - 1) {
                const int yr = r - (KS - 1);
                cs[yr * CSP + 8 + x] = s;          // contiguous, conflict-free
                // reflected pads: virtual col -x holds colsum[x];
                // virtual col x' in 256..263 holds colsum[510-x']
                if (x >= 1 && x <= 8)     cs[yr * CSP + 8 - x] = s;
                if (x >= 247 && x <= 254) cs[yr * CSP + 518 - x] = s;
            }
        }
    }
    __syncthreads();

    // ---- Stage B: horizontal 11-sum via b128 window reads, float4 store ----
    {
        const int l   = tid & 63;
        const int wid = tid >> 6;                  // wave id, 0..3
        const int X0  = l * 4;                     // lane's 4 output columns
#pragma unroll
        for (int rr = 0; rr < TILE_H / 4; ++rr) {  // 8 rows per wave
            const int row = wid + rr * 4;          // wave-uniform
            const float* rp = &cs[row * CSP + X0]; // 16B-aligned (X0, CSP mult 4)
            float4 q0 = *reinterpret_cast<const float4*>(rp);
            float4 q1 = *reinterpret_cast<const float4*>(rp + 4);
            float4 q2 = *reinterpret_cast<const float4*>(rp + 8);
            float4 q3 = *reinterpret_cast<const float4*>(rp + 12);
            float4 q4 = *reinterpret_cast<const float4*>(rp + 16);
            float v[20] = {q0.x, q0.y, q0.z, q0.w,
                           q1.x, q1.y, q1.z, q1.w,
                           q2.x, q2.y, q2.z, q2.w,
                           q3.x, q3.y, q3.z, q3.w,
                           q4.x, q4.y, q4.z, q4.w};
            // v[j] = colsum[X0 + j - 8]; out c needs j = c+3 .. c+13
            float s0 = v[3] + v[4] + v[5] + v[6] + v[7] + v[8] + v[9]
                     + v[10] + v[11] + v[12] + v[13];
            float s1 = s0 - v[3] + v[14];
            float s2 = s1 - v[4] + v[15];
            float s3 = s2 - v[5] + v[16];
            float4 o = make_float4(s0 * kv, s1 * kv, s2 * kv, s3 * kv);
            *reinterpret_cast<float4*>(dst + (size_t)(ty0 + row) * IMG_W + X0) = o;
        }
    }
}

extern "C" void kernel_launch(void* const* d_in, const int* in_sizes, int n_in,
                              void* d_out, int out_size, void* d_ws, size_t ws_size,
                              hipStream_t stream) {
    const float* in   = (const float*)d_in[0];
    const float* kern = (const float*)d_in[1];
    float*       out  = (float*)d_out;

    const int n_images = 16 * 64;                  // B * C
    dim3 grid(n_images * NTILES);                  // 8192 blocks
    dim3 block(256);
    blur_box11_kernel<<<grid, block, 0, stream>>>(in, kern, out);
}

// Round 4
// 145.733 us; speedup vs baseline: 1.3403x; 1.3403x over previous
//
#include <hip/hip_runtime.h>

// Depthwise 11x11 box blur, reflect pad, fp32, (16,64,256,256).
// Separable, fully register-resident: NO LDS data plane, NO barriers.
//
// Layout: lane owns 4 consecutive cols (float4); a wave's 64 lanes cover one
// full 256-col row. Each wave streams 8 output rows:
//   vertical:   2-pointer sliding sum  cs += in[refl(Y+5)] - in[refl(Y-6)]
//               (leaving row re-loaded from L2 instead of a ring buffer ->
//                low VGPR, high occupancy; intra-block re-reads are L2 hits)
//   horizontal: 11-tap via 10 __shfl (lane+-1,+-2) assembling the 14-col
//               window in registers, sliding-sum -> 4 outputs -> one float4
//               coalesced store. Reflect at image edges = exec-masked fixups
//               on lanes 0,1,62,63 (exactly the out-of-range shuffle slots).

#define PAD    5
#define IMG    256
#define TILE_H 32
#define RPW    8                       // rows per wave (4 waves x 8 = TILE_H)
#define NTILES (IMG / TILE_H)          // 8

__device__ __forceinline__ int refl(int r) {
    return (r < 0) ? -r : ((r > IMG - 1) ? 2 * (IMG - 1) - r : r);
}

__global__ __launch_bounds__(256)
void blur_box11_kernel(const float* __restrict__ in,
                       const float* __restrict__ kern,
                       float* __restrict__ out) {
    const int tid  = threadIdx.x;
    const int lane = tid & 63;
    const int wv   = tid >> 6;                     // 0..3
    const int img  = blockIdx.x >> 3;              // / NTILES
    const int ty0  = (blockIdx.x & (NTILES - 1)) * TILE_H;
    const int Y0   = ty0 + wv * RPW;               // wave's first output row
    const int X0   = lane * 4;                     // lane's 4 columns

    const float* src = in  + (size_t)img * (IMG * IMG);
    float*       dst = out + (size_t)img * (IMG * IMG);
    const float  kv  = kern[0];                    // 1/121 (uniform box)

    // ---- init vertical window: cs = sum of input rows Y0-5 .. Y0+5 ----
    float4 cs;
    {
        cs = *reinterpret_cast<const float4*>(src + refl(Y0 - PAD) * IMG + X0);
#pragma unroll
        for (int d = 1 - PAD; d <= PAD; ++d) {
            float4 b = *reinterpret_cast<const float4*>(src + refl(Y0 + d) * IMG + X0);
            cs.x += b.x; cs.y += b.y; cs.z += b.z; cs.w += b.w;
        }
    }

#pragma unroll
    for (int y = 0; y < RPW; ++y) {
        const int Y = Y0 + y;
        if (y > 0) {                               // slide window down one row
            float4 nv = *reinterpret_cast<const float4*>(src + refl(Y + PAD) * IMG + X0);
            float4 ov = *reinterpret_cast<const float4*>(src + refl(Y - PAD - 1) * IMG + X0);
            cs.x += nv.x - ov.x;
            cs.y += nv.y - ov.y;
            cs.z += nv.z - ov.z;
            cs.w += nv.w - ov.w;
        }

        // ---- horizontal: assemble cols X0-5 .. X0+8 (v0..v13) in regs ----
        float v0  = __shfl(cs.w, lane - 2);
        float v1  = __shfl(cs.x, lane - 1);
        float v2  = __shfl(cs.y, lane - 1);
        float v3  = __shfl(cs.z, lane - 1);
        float v4  = __shfl(cs.w, lane - 1);
        float v5  = cs.x, v6 = cs.y, v7 = cs.z, v8 = cs.w;
        float v9  = __shfl(cs.x, lane + 1);
        float v10 = __shfl(cs.y, lane + 1);
        float v11 = __shfl(cs.z, lane + 1);
        float v12 = __shfl(cs.w, lane + 1);
        float v13 = __shfl(cs.x, lane + 2);

        // reflect fixups (also repair the undefined out-of-range shuffles)
        if (lane == 0)       { v0 = v10; v1 = v9; v2 = v8; v3 = v7; v4 = v6; }
        else if (lane == 1)  { v0 = v2; }
        if (lane == 63)      { v9 = v7; v10 = v6; v11 = v5; v12 = v4; v13 = v3; }
        else if (lane == 62) { v13 = v11; }

        // sliding 11-sum over the 14-col window -> 4 outputs
        float s0 = ((v0 + v1) + (v2 + v3)) + ((v4 + v5) + (v6 + v7))
                 + ((v8 + v9) + v10);
        float s1 = s0 - v0 + v11;
        float s2 = s1 - v1 + v12;
        float s3 = s2 - v2 + v13;

        *reinterpret_cast<float4*>(dst + (size_t)Y * IMG + X0) =
            make_float4(s0 * kv, s1 * kv, s2 * kv, s3 * kv);
    }
}

extern "C" void kernel_launch(void* const* d_in, const int* in_sizes, int n_in,
                              void* d_out, int out_size, void* d_ws, size_t ws_size,
                              hipStream_t stream) {
    const float* in   = (const float*)d_in[0];
    const float* kern = (const float*)d_in[1];
    float*       out  = (float*)d_out;

    const int n_images = 16 * 64;                  // B * C
    dim3 grid(n_images * NTILES);                  // 8192 blocks
    dim3 block(256);
    blur_box11_kernel<<<grid, block, 0, stream>>>(in, kern, out);
}

// Round 5
// 90.021 us; speedup vs baseline: 2.1697x; 1.6189x over previous
//
#include <hip/hip_runtime.h>

// Depthwise 11x11 box blur, reflect pad, fp32, (16,64,256,256).
// Separable, register-resident vertical RING (no re-reads), shuffle horizontal.
// NO LDS data plane, NO barriers.
//
// Layout: lane owns 4 consecutive cols (f32x4); a wave's 64 lanes = one full
// 256-col row. Each wave streams a 64-row strip top-to-bottom (block = 4 waves
// = one whole 256-row image; grid = 1024 images = exactly 4 blocks/CU).
//
// Vertical: 11-deep float4 register ring, sliding sum cs += v_new - v_old.
//           Each input byte loaded ~1.16x total (74 loads / 64 output rows);
//           round 4's cache re-read (3.1x amplification ~= its entire
//           regression) is eliminated. 2-deep explicit prefetch (va/vb)
//           guarantees MLP >= 2 per wave.
// Horizontal: 11-tap via 10 __shfl assembling cols X0-5..X0+8 in registers,
//           sliding-sum -> 4 outputs -> one nontemporal float4 store
//           (output is never re-read; keep L2 for input).

typedef float f32x4 __attribute__((ext_vector_type(4)));

#define PAD   5
#define IMG   256
#define STRIP 64
#define PRE   (2 * PAD)          // 10 priming iterations
#define ITERS (STRIP + PRE)      // 74

__device__ __forceinline__ int refl(int r) {
    return (r < 0) ? -r : ((r > IMG - 1) ? 2 * (IMG - 1) - r : r);
}

__global__ __launch_bounds__(256, 4)
void blur_box11_kernel(const float* __restrict__ in,
                       const float* __restrict__ kern,
                       float* __restrict__ out) {
    const int lane = threadIdx.x & 63;
    const int wv   = threadIdx.x >> 6;             // 0..3
    const int img  = blockIdx.x;                   // 0..1023
    const int S    = wv * STRIP;                   // strip's first output row
    const int X0   = lane * 4;                     // lane's 4 columns

    const float* src = in  + (size_t)img * (IMG * IMG);
    float*       dst = out + (size_t)img * (IMG * IMG);
    const float  kv  = kern[0];                    // 1/121 (uniform box)

#define LOADROW(i) (*reinterpret_cast<const f32x4*>( \
        src + (size_t)refl(S - PAD + (i)) * IMG + X0))

    f32x4 ring[11];
#pragma unroll
    for (int k = 0; k < 11; ++k) ring[k] = (f32x4)0.0f;
    f32x4 cs = (f32x4)0.0f;

    f32x4 va = LOADROW(0);                         // 2-deep prefetch pipeline
    f32x4 vb = LOADROW(1);

#pragma unroll
    for (int i = 0; i < ITERS; ++i) {              // full unroll: ring idx static
        f32x4 v = va;
        va = vb;
        if (i + 2 < ITERS) vb = LOADROW(i + 2);

        cs += v - ring[i % 11];                    // vertical sliding 11-sum
        ring[i % 11] = v;

        if (i >= PRE) {
            const int row = S + i - PRE;           // output row S..S+63

            // assemble cols X0-5 .. X0+8 (v0..v13) in registers
            float v0  = __shfl(cs.w, lane - 2);
            float v1  = __shfl(cs.x, lane - 1);
            float v2  = __shfl(cs.y, lane - 1);
            float v3  = __shfl(cs.z, lane - 1);
            float v4  = __shfl(cs.w, lane - 1);
            float v5  = cs.x, v6 = cs.y, v7 = cs.z, v8 = cs.w;
            float v9  = __shfl(cs.x, lane + 1);
            float v10 = __shfl(cs.y, lane + 1);
            float v11 = __shfl(cs.z, lane + 1);
            float v12 = __shfl(cs.w, lane + 1);
            float v13 = __shfl(cs.x, lane + 2);

            // reflect fixups (also repair out-of-range shuffle slots)
            if (lane == 0)       { v0 = v10; v1 = v9; v2 = v8; v3 = v7; v4 = v6; }
            else if (lane == 1)  { v0 = v2; }
            if (lane == 63)      { v9 = v7; v10 = v6; v11 = v5; v12 = v4; v13 = v3; }
            else if (lane == 62) { v13 = v11; }

            // sliding 11-sum over the 14-col window -> 4 outputs
            float s0 = ((v0 + v1) + (v2 + v3)) + ((v4 + v5) + (v6 + v7))
                     + ((v8 + v9) + v10);
            float s1 = s0 - v0 + v11;
            float s2 = s1 - v1 + v12;
            float s3 = s2 - v2 + v13;

            f32x4 o;
            o.x = s0 * kv; o.y = s1 * kv; o.z = s2 * kv; o.w = s3 * kv;
            __builtin_nontemporal_store(
                o, reinterpret_cast<f32x4*>(dst + (size_t)row * IMG + X0));
        }
    }
#undef LOADROW
}

extern "C" void kernel_launch(void* const* d_in, const int* in_sizes, int n_in,
                              void* d_out, int out_size, void* d_ws, size_t ws_size,
                              hipStream_t stream) {
    const float* in   = (const float*)d_in[0];
    const float* kern = (const float*)d_in[1];
    float*       out  = (float*)d_out;

    const int n_images = 16 * 64;                  // B * C
    dim3 grid(n_images);                           // 1024 blocks, 4 waves each
    dim3 block(256);
    blur_box11_kernel<<<grid, block, 0, stream>>>(in, kern, out);
}